// Round 10
// baseline (407.656 us; speedup 1.0000x reference)
//
#include <hip/hip_runtime.h>
#include <hip/hip_bf16.h>
#include <cstdint>

// Problem constants
#define Bn   1024
#define Tn   128
#define En   300
#define Hn   100
#define Vn   50000
#define G4n  400   // 4*H
#define MPn  50048 // V padded to mult of 64
#define NPn  448   // 4H padded to mult of 16 (28 n-tiles; only 25 are real)
// gate-column PERMUTATION: jp = 4*u + q  <->  j = q*100 + u  (q = gate i,f,g,o)

typedef __bf16 bf16x8 __attribute__((ext_vector_type(8)));
typedef _Float16 half8 __attribute__((ext_vector_type(8)));
typedef _Float16 half2v __attribute__((ext_vector_type(2)));
typedef float  f32x4  __attribute__((ext_vector_type(4)));

// workspace byte offsets
#define OFF_TABLE  0ull         // f16 [Vn][448] permuted cols   44,800,000
#define OFF_WFRAG  44800000ull  // uint4 [28*4*64] W_hh frags       114,688
#define OFF_WFRAGB 44914688ull  // uint4 [10*28*64] W_ih B-frags    286,720
#define OFF_LLWT   45201408ull  // f32 [300][100] llW transposed    120,000
#define OFF_LV     45321408ull  // f32 [Bn][Hn]                     409,600
#define OFF_PN6    45731008ull  // f32 [Bn][6]                       24,576
#define OFF_OHG    45755584ull  // f16 [64 blk][Tn][100][16]     26,214,400

// fast sigmoid/tanh: v_rcp_f32 (1 instr) instead of IEEE divide (~9 instr).
__device__ __forceinline__ float sigf(float x) {
    return __builtin_amdgcn_rcpf(1.0f + __expf(-x));
}
__device__ __forceinline__ float tanhfast(float x) {
    return 1.0f - 2.0f * __builtin_amdgcn_rcpf(__expf(2.0f * x) + 1.0f);
}

// LDS-only barrier: drain lgkmcnt but leave vmcnt free-running so the table
// gather prefetch + oh global stores stay in flight across the barrier.
#define BAR_LDS() do {                                         \
    asm volatile("s_waitcnt lgkmcnt(0)" ::: "memory");          \
    __builtin_amdgcn_s_barrier();                               \
    asm volatile("" ::: "memory");                              \
} while (0)

// -------- K0: W_hh -> f16 frags; W_ih -> bf16 B-frags; llW -> transposed -----
__global__ void k_prep(const float* __restrict__ W_ih, const float* __restrict__ W_hh,
                       const float* __restrict__ llW,
                       uint4* __restrict__ wfrag, uint4* __restrict__ wfragB,
                       float* __restrict__ llwt) {
    int idx = blockIdx.x * 256 + threadIdx.x;
    if (idx < 28 * 4 * 64) {  // lane holds W[n=nt*16+(l&15)][k=kc*32+(l>>4)*8+j]
        int lane = idx & 63, tk = idx >> 6;
        int nt = tk >> 2, kc = tk & 3;
        int n = nt * 16 + (lane & 15);
        int k0 = kc * 32 + (lane >> 4) * 8;
        int q = n & 3, u = n >> 2;
        union { _Float16 h[8]; uint4 v; } pk;
#pragma unroll
        for (int j = 0; j < 8; j++) {
            int k = k0 + j;
            pk.h[j] = (_Float16)((u < Hn && k < Hn) ? W_hh[(size_t)(q * Hn + u) * Hn + k] : 0.0f);
        }
        wfrag[idx] = pk.v;
    }
    if (idx < 10 * 28 * 64) {  // W_ih frag (bf16): kc-major
        int lane = idx & 63, tk = idx >> 6;
        int kc = tk / 28, nsg = tk - kc * 28;
        int n = nsg * 16 + (lane & 15);
        int k0 = kc * 32 + (lane >> 4) * 8;
        int q = n & 3, u = n >> 2;
        union { __bf16 h[8]; uint4 v; } pk;
#pragma unroll
        for (int j = 0; j < 8; j++) {
            int k = k0 + j;
            pk.h[j] = (__bf16)((u < Hn && k < En) ? W_ih[(size_t)(q * Hn + u) * En + k] : 0.0f);
        }
        wfragB[idx] = pk.v;
    }
    if (idx < En * Hn) {  // llwt[k][h] = llW[h][k]
        int k = idx / Hn, h = idx - k * Hn;
        llwt[idx] = llW[(size_t)h * En + k];
    }
}

// -------- K1: table = emb @ W_ih^T + b (permuted cols, f16 out) --------------
__global__ __launch_bounds__(256, 2) void k_table(
    const float* __restrict__ emb, const uint4* __restrict__ wfragB,
    const float* __restrict__ b_ih, const float* __restrict__ b_hh,
    _Float16* __restrict__ table) {
    __shared__ __bf16 a_sh[64][328];   // 41,984 B (stride 328: rows offset 4 banks)
    const int tid = threadIdx.x;
    const int mt = blockIdx.x >> 1, nh = blockIdx.x & 1;

    // stage A: 64 rows x 320 cols (zeros past 300)
#pragma unroll
    for (int it = 0; it < 5; it++) {
        int x = it * 256 + tid;            // 0..1279
        int row = x / 20, seg = x - row * 20;
        int gr = mt * 64 + row;
        const float* ar = emb + (size_t)(gr < Vn ? gr : Vn - 1) * En;
        int c0 = seg * 16;
        union { __bf16 h[16]; bf16x8 v[2]; } pk;
#pragma unroll
        for (int g = 0; g < 4; g++) {
            int c = c0 + g * 4;
            if (c + 4 <= En) {
                float4 f = *(const float4*)(ar + c);
                pk.h[g * 4 + 0] = (__bf16)f.x; pk.h[g * 4 + 1] = (__bf16)f.y;
                pk.h[g * 4 + 2] = (__bf16)f.z; pk.h[g * 4 + 3] = (__bf16)f.w;
            } else {
                pk.h[g * 4 + 0] = (__bf16)0.f; pk.h[g * 4 + 1] = (__bf16)0.f;
                pk.h[g * 4 + 2] = (__bf16)0.f; pk.h[g * 4 + 3] = (__bf16)0.f;
            }
        }
        *(bf16x8*)&a_sh[row][c0] = pk.v[0];
        *(bf16x8*)&a_sh[row][c0 + 8] = pk.v[1];
    }
    __syncthreads();

    const int wv = tid >> 6, l = tid & 63;
    const int c16 = l & 15, quad = l >> 4;
    f32x4 acc[14];
#pragma unroll
    for (int i = 0; i < 14; i++) acc[i] = (f32x4){0.f, 0.f, 0.f, 0.f};

    uint4 bcur[14];
#pragma unroll
    for (int ns = 0; ns < 14; ns++) bcur[ns] = wfragB[((0 * 28 + nh * 14 + ns) << 6) + l];

    for (int kc = 0; kc < 10; kc++) {
        uint4 bnxt[14];
        if (kc < 9) {
#pragma unroll
            for (int ns = 0; ns < 14; ns++) bnxt[ns] = wfragB[(((kc + 1) * 28 + nh * 14 + ns) << 6) + l];
        }
        bf16x8 af = *(const bf16x8*)&a_sh[wv * 16 + c16][kc * 32 + quad * 8];
#pragma unroll
        for (int ns = 0; ns < 14; ns++)
            acc[ns] = __builtin_amdgcn_mfma_f32_16x16x32_bf16(af, __builtin_bit_cast(bf16x8, bcur[ns]), acc[ns], 0, 0, 0);
        if (kc < 9) {
#pragma unroll
            for (int ns = 0; ns < 14; ns++) bcur[ns] = bnxt[ns];
        }
    }
    // epilogue: C/D row = quad*4+r, col = c16
#pragma unroll
    for (int ns = 0; ns < 14; ns++) {
        int n = (nh * 14 + ns) * 16 + c16;
        int q = n & 3, u = n >> 2;
        if (u < Hn) {
            int j = q * Hn + u;
            float bias = b_ih[j] + b_hh[j];
#pragma unroll
            for (int r = 0; r < 4; r++) {
                int m = mt * 64 + wv * 16 + quad * 4 + r;
                if (m < Vn) table[(size_t)m * NPn + n] = (_Float16)(acc[ns][r] + bias);
            }
        }
    }
}

// -------- K2: label_vec = emb[lid] @ ll_W^T + ll_b (2-way K split) -----------
__global__ void k_label(const int* __restrict__ lwid, const float* __restrict__ emb,
                        const float* __restrict__ llwt, const float* __restrict__ llb,
                        float* __restrict__ lv) {
    __shared__ float er[En];
    __shared__ float part[Hn];
    int b = blockIdx.x;
    int lid = lwid[b];
    for (int k = threadIdx.x; k < En; k += 256) er[k] = emb[(size_t)lid * En + k];
    __syncthreads();
    int h = threadIdx.x & 127, half = threadIdx.x >> 7;
    float acc = 0.f;
    if (h < Hn) {
        int k0 = half * 150, k1 = k0 + 150;
        for (int k = k0; k < k1; k++) acc += er[k] * llwt[k * Hn + h];
        if (half == 1) part[h] = acc;
    }
    __syncthreads();
    if (h < Hn && half == 0) lv[(size_t)b * Hn + h] = acc + part[h] + llb[h];
}

// -------- K3: fused LSTM, 16 batch/block, grid 64, zero-waste MFMA -----------
// R10: batch dim fills ALL 16 MFMA columns. B[k][col=c16] = h[batch c16][k]
// -> ONE MFMA per tile serves 16 batches (4x fewer MFMAs/batch than R8, 8x
// than R9). D col = c16 = batch, row = quad*4+r -> lane (c16,quad) holds
// (i,f,g,o) of u=(TB+i)*4+quad for batch c16, lane-local, no dup select.
// Each lane owns NT (6-7) items -> 7-way ILP in the pointwise phase replaces
// TLP (grid 64, 1 block/CU, 1 wave/SIMD, launch_bounds(256,1): VGPR budget
// up to 512, no occupancy constraint). oh history -> GLOBAL (410KB > LDS),
// coalesced 16-batch-contiguous stores; drained only at final barrier.
__global__ __launch_bounds__(256, 1) void k_lstm(
    const int* __restrict__ word_id, const int* __restrict__ sen_len,
    const _Float16* __restrict__ table, const uint4* __restrict__ wfrag,
    const float* __restrict__ lv, const float* __restrict__ linW,
    const float* __restrict__ linb, _Float16* __restrict__ ohg,
    float* __restrict__ pn6, float* __restrict__ d_out) {
    __shared__ __align__(16) _Float16 h_cur[2][16][136];  // [parity][bat][136], cols>=100 zero
    __shared__ __align__(16) float    spw[16][Tn][4];     // [bat][t][wave]
    __shared__ int      widc[16][Tn];                     // premultiplied wid*NPn
    __shared__ float    pos_sh[16][Hn];
    __shared__ float    lasth_sh[16][Hn];
    __shared__ float    neg_sh[16][Hn];
    __shared__ float    tk_val[16][4];
    __shared__ int      tk_idx[16][4];

    const int tid = threadIdx.x;
    const int w = tid >> 6, l = tid & 63;
    const int c16 = l & 15, quad = l >> 4;
    const int b0 = blockIdx.x * 16;

    // init: zero both h parities; stage premultiplied word ids
    for (int i = tid; i < 2176; i += 256) ((uint32_t*)h_cur)[i] = 0u;
    for (int i = tid; i < 2048; i += 256)
        widc[i >> 7][i & 127] = word_id[(b0 + (i >> 7)) * Tn + (i & 127)] * NPn;

    // wave tile split over the 25 real tiles: w0 -> 7, w1..3 -> 6
    const bool has7 = (w == 0);
    const int TB = has7 ? 0 : 7 + 6 * (w - 1);
    const int NT = has7 ? 7 : 6;
#define IF_ITEM(i) if ((i) < 6 || has7)

    // persistent W_hh fragments — the A operand
    half8 bfr[7][4];
#pragma unroll
    for (int kc = 0; kc < 4; kc++) {
#pragma unroll
        for (int i = 0; i < 6; i++)
            bfr[i][kc] = __builtin_bit_cast(half8, wfrag[((TB + i) * 4 + kc) * 64 + l]);
        bfr[6][kc] = has7 ? __builtin_bit_cast(half8, wfrag[((TB + 6) * 4 + kc) * 64 + l])
                          : bfr[5][kc];
    }

    // lane identity: batch = c16; items i -> u = (TB+i)*4 + quad
    const int bat = c16;
    const int slen = sen_len[b0 + bat];
    int u4o[7], u16o[7], uho[7];
    float lt[7];
#pragma unroll
    for (int i = 0; i < 7; i++) {
        int ui = (TB + i) * 4 + quad;
        u4o[i] = ui * 4; u16o[i] = ui * 16; uho[i] = bat * 136 + ui;
        lt[i] = 0.f;
        IF_ITEM(i) lt[i] = lv[(size_t)(b0 + bat) * Hn + ui];
    }

    __syncthreads();

    uint2 xq[7], xq1[7];
    {
        int w0o = widc[bat][0], w1o = widc[bat][1];
#pragma unroll
        for (int i = 0; i < 7; i++) {
            xq[i] = (uint2){0, 0}; xq1[i] = (uint2){0, 0};
            IF_ITEM(i) {
                xq[i]  = *(const uint2*)(table + w0o + u4o[i]);
                xq1[i] = *(const uint2*)(table + w1o + u4o[i]);
            }
        }
    }

    float creg[7], sumh[7], lastv[7];
#pragma unroll
    for (int i = 0; i < 7; i++) { creg[i] = 0.f; sumh[i] = 0.f; lastv[i] = 0.f; }
    float p_carry = 0.f;
    _Float16* ohg_t = ohg + (size_t)blockIdx.x * Tn * 1600;

    for (int t = 0; t < Tn; t++) {
        // ---- B-fragments: h of batch c16 (4 ds_read_b128, shared by all tiles)
        const _Float16* hp = &h_cur[t & 1][0][0] + bat * 136;
        half8 hf0 = *(const half8*)(hp + 0 * 32 + quad * 8);
        half8 hf1 = *(const half8*)(hp + 1 * 32 + quad * 8);
        half8 hf2 = *(const half8*)(hp + 2 * 32 + quad * 8);
        half8 hf3 = *(const half8*)(hp + 3 * 32 + quad * 8);
        // ---- MFMA: D = W_hh . H16 — one chain per tile, serves 16 batches
        f32x4 acc[7];
#pragma unroll
        for (int i = 0; i < 7; i++) {
            IF_ITEM(i) {
                acc[i] = __builtin_amdgcn_mfma_f32_16x16x32_f16(bfr[i][0], hf0, (f32x4){0.f, 0.f, 0.f, 0.f}, 0, 0, 0);
                acc[i] = __builtin_amdgcn_mfma_f32_16x16x32_f16(bfr[i][1], hf1, acc[i], 0, 0, 0);
                acc[i] = __builtin_amdgcn_mfma_f32_16x16x32_f16(bfr[i][2], hf2, acc[i], 0, 0, 0);
                acc[i] = __builtin_amdgcn_mfma_f32_16x16x32_f16(bfr[i][3], hf3, acc[i], 0, 0, 0);
            } else acc[i] = (f32x4){0.f, 0.f, 0.f, 0.f};
        }
        // ---- deferred score reduce (t-1): cross-quad sum, same batch
        {
            float pr = p_carry;
            pr += __shfl_xor(pr, 16, 64);
            pr += __shfl_xor(pr, 32, 64);
            if (quad == 0 && t > 0) spw[bat][t - 1][w] = pr;
        }
        // ---- pointwise: 7 independent items (ILP hides transcendental chain)
        float p = 0.f;
        _Float16* oh_row = ohg_t;
#pragma unroll
        for (int i = 0; i < 7; i++) {
            IF_ITEM(i) {
                half2v x01 = __builtin_bit_cast(half2v, xq[i].x);
                half2v x23 = __builtin_bit_cast(half2v, xq[i].y);
                float gi = acc[i][0] + (float)x01.x;
                float gf = acc[i][1] + (float)x01.y;
                float gg = acc[i][2] + (float)x23.x;
                float go = acc[i][3] + (float)x23.y;
                float c = sigf(gf) * creg[i] + sigf(gi) * tanhfast(gg);
                creg[i] = c;
                float hh = sigf(go) * tanhfast(c);
                _Float16 h16 = (_Float16)hh;
                h_cur[(t + 1) & 1][0][uho[i]] = h16;
                oh_row[u16o[i] + bat] = h16;
                if (t < slen) sumh[i] += hh;
                if (t == slen - 1) lastv[i] = hh;
                p += hh * lt[i];
            }
        }
        // ---- 2-deep table prefetch
        {
            int tn2 = (t + 2 < Tn) ? t + 2 : Tn - 1;
            int wno = widc[bat][tn2];
#pragma unroll
            for (int i = 0; i < 7; i++) {
                xq[i] = xq1[i];
                IF_ITEM(i) xq1[i] = *(const uint2*)(table + wno + u4o[i]);
            }
        }
        p_carry = p;
        ohg_t += 1600;
        BAR_LDS();  // h(t+1)+spw visible; vmcnt (gathers+oh stores) stays free
    }
    // final deferred reduce for t = Tn-1
    {
        float pr = p_carry;
        pr += __shfl_xor(pr, 16, 64);
        pr += __shfl_xor(pr, 32, 64);
        if (quad == 0) spw[bat][Tn - 1][w] = pr;
    }
    __syncthreads();  // drains vmcnt: oh stores complete before epilogue reads
    // ---- top-4: wave w handles batches w*4..w*4+3; tie-break smaller index
    const _Float16* oh_gb = ohg + (size_t)blockIdx.x * Tn * 1600;
    for (int j = 0; j < 4; j++) {
        int kb = w * 4 + j;
        int sl = sen_len[b0 + kb];
        float4 a0 = *(const float4*)&spw[kb][l][0];
        float4 c0 = *(const float4*)&spw[kb][l + 64][0];
        float sa = (a0.x + a0.y) + (a0.z + a0.w);
        float sb = (c0.x + c0.y) + (c0.z + c0.w);
        float s0 = (l < sl) ? sa : -1e30f;
        float s1 = (l + 64 < sl) ? sb : -1e30f;
        bool tk0 = false, tk1 = false;
#pragma unroll
        for (int p4 = 0; p4 < 4; p4++) {
            float v = tk0 ? -1e30f : s0;
            int ix = l;
            float v1 = tk1 ? -1e30f : s1;
            if (v1 > v) { v = v1; ix = l + 64; }
            for (int off = 32; off; off >>= 1) {
                float ov = __shfl_down(v, off, 64);
                int oi = __shfl_down(ix, off, 64);
                if (ov > v || (ov == v && oi < ix)) { v = ov; ix = oi; }
            }
            v = __shfl(v, 0, 64);
            ix = __shfl(ix, 0, 64);
            if (l == 0) { tk_val[kb][p4] = v; tk_idx[kb][p4] = ix; }
            if (ix == l) tk0 = true;
            if (ix == l + 64) tk1 = true;
        }
    }
    __syncthreads();
    // ---- pos / neg / lasth per item (gathers own-written oh from global)
    {
        int ix0 = tk_idx[bat][0] * 1600, ix1 = tk_idx[bat][1] * 1600;
        int ix2 = tk_idx[bat][2] * 1600, ix3 = tk_idx[bat][3] * 1600;
        float v0 = tk_val[bat][0], v1 = tk_val[bat][1];
        float v2 = tk_val[bat][2], v3 = tk_val[bat][3];
#pragma unroll
        for (int i = 0; i < 7; i++) {
            IF_ITEM(i) {
                int uo = u16o[i] + bat;
                float r0 = (float)oh_gb[ix0 + uo];
                float r1 = (float)oh_gb[ix1 + uo];
                float r2 = (float)oh_gb[ix2 + uo];
                float r3 = (float)oh_gb[ix3 + uo];
                float pos = v0 * r0 + v1 * r1 + v2 * r2 + v3 * r3;
                float nsum = sumh[i] - ((r0 + r1) + (r2 + r3));
                int ui = u4o[i] >> 2;
                pos_sh[bat][ui] = pos;
                lasth_sh[bat][ui] = lastv[i];
                neg_sh[bat][ui] = nsum;
            }
        }
    }
    __syncthreads();
    // ---- projections: 16 batches x {out_f, l_rep, pn6} x 6
    for (int x = tid; x < 288; x += 256) {
        int which = x / 96, r = x - which * 96;
        int pmb = r / 6, o = r - pmb * 6;
        const float* src = (which == 0) ? &lasth_sh[pmb][0]
                         : (which == 1) ? &pos_sh[pmb][0] : &neg_sh[pmb][0];
        float acc2 = (which == 2) ? 0.f : linb[o];
        for (int uu = 0; uu < Hn; uu++) acc2 += src[uu] * linW[o * Hn + uu];
        if (which == 0)      d_out[(b0 + pmb) * 6 + o] = acc2;
        else if (which == 1) d_out[Bn * 6 + (b0 + pmb) * 6 + o] = acc2;
        else                 pn6[(b0 + pmb) * 6 + o] = acc2;  // bias added post-cumsum
    }
#undef IF_ITEM
}

// -------- K4: r_rep = cumsum_b(pn6) + linb (wave-shuffle scan, writes d_out) -
__global__ __launch_bounds__(1024) void k_scan6(const float* __restrict__ pn6,
                                                const float* __restrict__ linb,
                                                float* __restrict__ d_out) {
    __shared__ float wsum[16];
    __shared__ float wpre[16];
    int o = blockIdx.x, t = threadIdx.x;
    int lane = t & 63, wv = t >> 6;
    float v = pn6[t * 6 + o];
#pragma unroll
    for (int off = 1; off < 64; off <<= 1) {
        float x = __shfl_up(v, off, 64);
        if (lane >= off) v += x;
    }
    if (lane == 63) wsum[wv] = v;
    __syncthreads();
    if (t < 16) {
        float s = wsum[t];
#pragma unroll
        for (int off = 1; off < 16; off <<= 1) {
            float x = __shfl_up(s, off, 64);
            if (t >= off) s += x;
        }
        wpre[t] = s;
    }
    __syncthreads();
    float pre = wv ? wpre[wv - 1] : 0.f;
    d_out[2 * Bn * 6 + t * 6 + o] = v + pre + linb[o];
}

extern "C" void kernel_launch(void* const* d_in, const int* in_sizes, int n_in,
                              void* d_out, int out_size, void* d_ws, size_t ws_size,
                              hipStream_t stream) {
    const int*   word_id = (const int*)d_in[0];
    const int*   sen_len = (const int*)d_in[1];
    const int*   lwid    = (const int*)d_in[2];
    const float* emb     = (const float*)d_in[3];
    const float* W_ih    = (const float*)d_in[4];
    const float* W_hh    = (const float*)d_in[5];
    const float* b_ih    = (const float*)d_in[6];
    const float* b_hh    = (const float*)d_in[7];
    const float* linW    = (const float*)d_in[8];
    const float* linb    = (const float*)d_in[9];
    const float* llW     = (const float*)d_in[10];
    const float* llb     = (const float*)d_in[11];

    char* ws = (char*)d_ws;
    _Float16* table  = (_Float16*)(ws + OFF_TABLE);
    uint4*    wfrag  = (uint4*)(ws + OFF_WFRAG);
    uint4*    wfragB = (uint4*)(ws + OFF_WFRAGB);
    float*    llwt   = (float*)(ws + OFF_LLWT);
    float*    lvp    = (float*)(ws + OFF_LV);
    float*    pn6    = (float*)(ws + OFF_PN6);
    _Float16* ohg    = (_Float16*)(ws + OFF_OHG);
    float*    outp   = (float*)d_out;

    k_prep<<<118, 256, 0, stream>>>(W_ih, W_hh, llW, wfrag, wfragB, llwt);
    k_table<<<(MPn / 64) * 2, 256, 0, stream>>>(emb, wfragB, b_ih, b_hh, table);
    k_label<<<Bn, 256, 0, stream>>>(lwid, emb, llwt, llb, lvp);
    k_lstm<<<Bn / 16, 256, 0, stream>>>(word_id, sen_len, table, wfrag, lvp,
                                        linW, linb, ohg, pn6, outp);
    k_scan6<<<6, 1024, 0, stream>>>(pn6, linb, outp);
}

// Round 11
// 273.472 us; speedup vs baseline: 1.4907x; 1.4907x over previous
//
#include <hip/hip_runtime.h>
#include <hip/hip_bf16.h>
#include <cstdint>

// Problem constants
#define Bn   1024
#define Tn   128
#define En   300
#define Hn   100
#define Vn   50000
#define G4n  400   // 4*H
#define MPn  50048 // V padded to mult of 64
#define NPn  448   // 4H padded to mult of 16 (28 n-tiles; only 25 are real)
// gate-column PERMUTATION: jp = 4*u + q  <->  j = q*100 + u  (q = gate i,f,g,o)

typedef __bf16 bf16x8 __attribute__((ext_vector_type(8)));
typedef _Float16 half8 __attribute__((ext_vector_type(8)));
typedef _Float16 half2v __attribute__((ext_vector_type(2)));
typedef float  f32x4  __attribute__((ext_vector_type(4)));

// workspace byte offsets
#define OFF_TABLE  0ull         // f16 [Vn][448] permuted cols   44,800,000
#define OFF_WFRAG  44800000ull  // uint4 [28*4*64] W_hh frags       114,688
#define OFF_WFRAGB 44914688ull  // uint4 [10*28*64] W_ih frags      286,720
#define OFF_LLWT   45201408ull  // f32 [300][100] llW transposed    120,000
#define OFF_LV     45321408ull  // f32 [Bn][Hn]                     409,600
#define OFF_PN6    45731008ull  // f32 [Bn][6]                       24,576

// fast sigmoid/tanh: v_rcp_f32 (1 instr) instead of IEEE divide (~9 instr).
__device__ __forceinline__ float sigf(float x) {
    return __builtin_amdgcn_rcpf(1.0f + __expf(-x));
}
__device__ __forceinline__ float tanhfast(float x) {
    return 1.0f - 2.0f * __builtin_amdgcn_rcpf(__expf(2.0f * x) + 1.0f);
}

// LDS-only barrier: drain lgkmcnt but leave vmcnt free-running so the table
// gather prefetch stays in flight across the barrier.
#define BAR_LDS() do {                                         \
    asm volatile("s_waitcnt lgkmcnt(0)" ::: "memory");          \
    __builtin_amdgcn_s_barrier();                               \
    asm volatile("" ::: "memory");                              \
} while (0)

// -------- K0: W_hh -> f16 frags; W_ih -> bf16 frags; llW -> transposed -------
__global__ void k_prep(const float* __restrict__ W_ih, const float* __restrict__ W_hh,
                       const float* __restrict__ llW,
                       uint4* __restrict__ wfrag, uint4* __restrict__ wfragB,
                       float* __restrict__ llwt) {
    int idx = blockIdx.x * 256 + threadIdx.x;
    if (idx < 28 * 4 * 64) {  // lane holds W[n=nt*16+(l&15)][k=kc*32+(l>>4)*8+j]
        int lane = idx & 63, tk = idx >> 6;
        int nt = tk >> 2, kc = tk & 3;
        int n = nt * 16 + (lane & 15);
        int k0 = kc * 32 + (lane >> 4) * 8;
        int q = n & 3, u = n >> 2;
        union { _Float16 h[8]; uint4 v; } pk;
#pragma unroll
        for (int j = 0; j < 8; j++) {
            int k = k0 + j;
            pk.h[j] = (_Float16)((u < Hn && k < Hn) ? W_hh[(size_t)(q * Hn + u) * Hn + k] : 0.0f);
        }
        wfrag[idx] = pk.v;
    }
    if (idx < 10 * 28 * 64) {  // W_ih frag (bf16): kc-major
        int lane = idx & 63, tk = idx >> 6;
        int kc = tk / 28, nsg = tk - kc * 28;
        int n = nsg * 16 + (lane & 15);
        int k0 = kc * 32 + (lane >> 4) * 8;
        int q = n & 3, u = n >> 2;
        union { __bf16 h[8]; uint4 v; } pk;
#pragma unroll
        for (int j = 0; j < 8; j++) {
            int k = k0 + j;
            pk.h[j] = (__bf16)((u < Hn && k < En) ? W_ih[(size_t)(q * Hn + u) * En + k] : 0.0f);
        }
        wfragB[idx] = pk.v;
    }
    if (idx < En * Hn) {  // llwt[k][h] = llW[h][k]
        int k = idx / Hn, h = idx - k * Hn;
        llwt[idx] = llW[(size_t)h * En + k];
    }
}

// -------- K1: table = emb @ W_ih^T + b (permuted cols, f16 out) --------------
// R11: SWAPPED-OPERAND epilogue (same duality as k_lstm R7): A = wfragB frag
// (row = n), B = emb a_sh fragment (col = m, identical ds_read as before).
// D[row = n = tile*16 + quad*4 + r][col = m = wv*16 + c16]: each lane holds
// 4 CONSECUTIVE n (r=0..3 = gates i,f,g,o of u = tile*4+quad) for one m ->
// epilogue packs them into ONE 8-byte store. 56 scalar 2B stores -> 14x 8B.
__global__ __launch_bounds__(256, 2) void k_table(
    const float* __restrict__ emb, const uint4* __restrict__ wfragB,
    const float* __restrict__ b_ih, const float* __restrict__ b_hh,
    _Float16* __restrict__ table) {
    __shared__ __bf16 a_sh[64][328];   // 41,984 B (stride 328: rows offset 4 banks)
    const int tid = threadIdx.x;
    const int mt = blockIdx.x >> 1, nh = blockIdx.x & 1;

    // stage A: 64 rows x 320 cols (zeros past 300)
#pragma unroll
    for (int it = 0; it < 5; it++) {
        int x = it * 256 + tid;            // 0..1279
        int row = x / 20, seg = x - row * 20;
        int gr = mt * 64 + row;
        const float* ar = emb + (size_t)(gr < Vn ? gr : Vn - 1) * En;
        int c0 = seg * 16;
        union { __bf16 h[16]; bf16x8 v[2]; } pk;
#pragma unroll
        for (int g = 0; g < 4; g++) {
            int c = c0 + g * 4;
            if (c + 4 <= En) {
                float4 f = *(const float4*)(ar + c);
                pk.h[g * 4 + 0] = (__bf16)f.x; pk.h[g * 4 + 1] = (__bf16)f.y;
                pk.h[g * 4 + 2] = (__bf16)f.z; pk.h[g * 4 + 3] = (__bf16)f.w;
            } else {
                pk.h[g * 4 + 0] = (__bf16)0.f; pk.h[g * 4 + 1] = (__bf16)0.f;
                pk.h[g * 4 + 2] = (__bf16)0.f; pk.h[g * 4 + 3] = (__bf16)0.f;
            }
        }
        *(bf16x8*)&a_sh[row][c0] = pk.v[0];
        *(bf16x8*)&a_sh[row][c0 + 8] = pk.v[1];
    }
    __syncthreads();

    const int wv = tid >> 6, l = tid & 63;
    const int c16 = l & 15, quad = l >> 4;
    f32x4 acc[14];
#pragma unroll
    for (int i = 0; i < 14; i++) acc[i] = (f32x4){0.f, 0.f, 0.f, 0.f};

    uint4 bcur[14];
#pragma unroll
    for (int ns = 0; ns < 14; ns++) bcur[ns] = wfragB[((0 * 28 + nh * 14 + ns) << 6) + l];

    for (int kc = 0; kc < 10; kc++) {
        uint4 bnxt[14];
        if (kc < 9) {
#pragma unroll
            for (int ns = 0; ns < 14; ns++) bnxt[ns] = wfragB[(((kc + 1) * 28 + nh * 14 + ns) << 6) + l];
        }
        bf16x8 af = *(const bf16x8*)&a_sh[wv * 16 + c16][kc * 32 + quad * 8];
#pragma unroll
        for (int ns = 0; ns < 14; ns++)
            acc[ns] = __builtin_amdgcn_mfma_f32_16x16x32_bf16(__builtin_bit_cast(bf16x8, bcur[ns]), af, acc[ns], 0, 0, 0);
        if (kc < 9) {
#pragma unroll
            for (int ns = 0; ns < 14; ns++) bcur[ns] = bnxt[ns];
        }
    }
    // epilogue (swapped): lane (c16,quad) holds n = n0..n0+3 for m.
    const int m = mt * 64 + wv * 16 + c16;
    if (m < Vn) {
        _Float16* trow = table + (size_t)m * NPn;
#pragma unroll
        for (int ns = 0; ns < 14; ns++) {
            int n0 = (nh * 14 + ns) * 16 + quad * 4;
            int u = n0 >> 2;                       // = (nh*14+ns)*4 + quad
            union { _Float16 h[4]; uint2 v; } pk;
            if (u < Hn) {
#pragma unroll
                for (int r = 0; r < 4; r++) {
                    int j = r * Hn + u;            // q = r (n0 is mult of 4)
                    pk.h[r] = (_Float16)(acc[ns][r] + b_ih[j] + b_hh[j]);
                }
            } else {
                pk.h[0] = (_Float16)0.f; pk.h[1] = (_Float16)0.f;
                pk.h[2] = (_Float16)0.f; pk.h[3] = (_Float16)0.f;
            }
            *(uint2*)(trow + n0) = pk.v;
        }
    }
}

// -------- K2: label_vec = emb[lid] @ ll_W^T + ll_b (2-way K split) -----------
__global__ void k_label(const int* __restrict__ lwid, const float* __restrict__ emb,
                        const float* __restrict__ llwt, const float* __restrict__ llb,
                        float* __restrict__ lv) {
    __shared__ float er[En];
    __shared__ float part[Hn];
    int b = blockIdx.x;
    int lid = lwid[b];
    for (int k = threadIdx.x; k < En; k += 256) er[k] = emb[(size_t)lid * En + k];
    __syncthreads();
    int h = threadIdx.x & 127, half = threadIdx.x >> 7;
    float acc = 0.f;
    if (h < Hn) {
        int k0 = half * 150, k1 = k0 + 150;
        for (int k = k0; k < k1; k++) acc += er[k] * llwt[k * Hn + h];
        if (half == 1) part[h] = acc;
    }
    __syncthreads();
    if (h < Hn && half == 0) lv[(size_t)b * Hn + h] = acc + part[h] + llb[h];
}

// -------- K3: fused LSTM, 4 batch/block, 8 waves, SWAPPED-OPERAND MFMA -------
// (R7 verbatim — best measured k_lstm config: ~110 us.)
__global__ __launch_bounds__(512, 2) void k_lstm(
    const int* __restrict__ word_id, const int* __restrict__ sen_len,
    const _Float16* __restrict__ table, const uint4* __restrict__ wfrag,
    const float* __restrict__ lv, const float* __restrict__ linW,
    const float* __restrict__ linb, float* __restrict__ pn6,
    float* __restrict__ d_out) {
    __shared__ __align__(16) _Float16 h_cur[2][4][144];   // [parity][mb][144], cols>=100 zero
    __shared__ __align__(16) _Float16 oh_lds[4][12832];   // [mb][t*100+u] (+32 pad)
    __shared__ __align__(16) float    spw[4][Tn][8];      // [mb][t][wave]
    __shared__ int      widc[4][Tn];                      // premultiplied wid*NPn
    __shared__ float    pos_sh[4][Hn];
    __shared__ float    lasth_sh[4][Hn];
    __shared__ float    neg_sh[4][Hn];
    __shared__ float    tk_val[4][4];
    __shared__ int      tk_idx[4][4];

    const int tid = threadIdx.x;
    const int w = tid >> 6, l = tid & 63;
    const int c16 = l & 15, quad = l >> 4;
    const int b0 = blockIdx.x * 4;

    // init: zero both h parities (incl. padding cols); stage word ids
    for (int i = tid; i < 576; i += 512) ((uint32_t*)h_cur)[i] = 0u;
    { int imb = tid >> 7, it = tid & 127; widc[imb][it] = word_id[(b0 + imb) * Tn + it] * NPn; }

    // wave tile assignment over the 25 REAL tiles: w0 -> 4 tiles, w1..7 -> 3.
    const bool has4 = (w == 0);
    const int TB = has4 ? 0 : 4 + 3 * (w - 1);
    const int NT = has4 ? 4 : 3;

    // persistent W_hh fragments — the A operand
    half8 bfr[4][4];
#pragma unroll
    for (int kc = 0; kc < 4; kc++) {
        bfr[0][kc] = __builtin_bit_cast(half8, wfrag[((TB + 0) * 4 + kc) * 64 + l]);
        bfr[1][kc] = __builtin_bit_cast(half8, wfrag[((TB + 1) * 4 + kc) * 64 + l]);
        bfr[2][kc] = __builtin_bit_cast(half8, wfrag[((TB + 2) * 4 + kc) * 64 + l]);
        if (has4) bfr[3][kc] = __builtin_bit_cast(half8, wfrag[((TB + 3) * 4 + kc) * 64 + l]);
    }

    // lane work identity: dup group selects the consumed tile
    const int mb = c16 & 3, dup = c16 >> 2;
    const bool act = (dup < NT);
    const int u = (TB + dup) * 4 + quad;     // <100 whenever act
    const int slen = act ? sen_len[b0 + mb] : 0;
    const float lt_reg = act ? lv[(size_t)(b0 + mb) * Hn + u] : 0.f;
    const _Float16* tb_u = table + u * 4;

    __syncthreads();

    uint2 xq = {0, 0}, xq1 = {0, 0};
    if (act) {
        xq  = *(const uint2*)(tb_u + (size_t)widc[mb][0]);
        xq1 = *(const uint2*)(tb_u + (size_t)widc[mb][1]);
    }

    float c_reg = 0.f, sumh = 0.f, lasth = 0.f;
    float p_carry = 0.f;

    for (int t = 0; t < Tn; t++) {
        // ---- B-fragments: h for batch c16&3
        const _Float16* hp = &h_cur[t & 1][0][0];
        half8 hf0 = *(const half8*)(hp + (c16 & 3) * 144 + 0 * 32 + quad * 8);
        half8 hf1 = *(const half8*)(hp + (c16 & 3) * 144 + 1 * 32 + quad * 8);
        half8 hf2 = *(const half8*)(hp + (c16 & 3) * 144 + 2 * 32 + quad * 8);
        half8 hf3 = *(const half8*)(hp + (c16 & 3) * 144 + 3 * 32 + quad * 8);
        // ---- MFMA: D = W_hh . h  (gates land lane-local)
        f32x4 acc0, acc1, acc2, acc3;
        acc0 = __builtin_amdgcn_mfma_f32_16x16x32_f16(bfr[0][0], hf0, (f32x4){0.f, 0.f, 0.f, 0.f}, 0, 0, 0);
        acc1 = __builtin_amdgcn_mfma_f32_16x16x32_f16(bfr[1][0], hf0, (f32x4){0.f, 0.f, 0.f, 0.f}, 0, 0, 0);
        acc2 = __builtin_amdgcn_mfma_f32_16x16x32_f16(bfr[2][0], hf0, (f32x4){0.f, 0.f, 0.f, 0.f}, 0, 0, 0);
        if (has4) acc3 = __builtin_amdgcn_mfma_f32_16x16x32_f16(bfr[3][0], hf0, (f32x4){0.f, 0.f, 0.f, 0.f}, 0, 0, 0);
        acc0 = __builtin_amdgcn_mfma_f32_16x16x32_f16(bfr[0][1], hf1, acc0, 0, 0, 0);
        acc1 = __builtin_amdgcn_mfma_f32_16x16x32_f16(bfr[1][1], hf1, acc1, 0, 0, 0);
        acc2 = __builtin_amdgcn_mfma_f32_16x16x32_f16(bfr[2][1], hf1, acc2, 0, 0, 0);
        if (has4) acc3 = __builtin_amdgcn_mfma_f32_16x16x32_f16(bfr[3][1], hf1, acc3, 0, 0, 0);
        acc0 = __builtin_amdgcn_mfma_f32_16x16x32_f16(bfr[0][2], hf2, acc0, 0, 0, 0);
        acc1 = __builtin_amdgcn_mfma_f32_16x16x32_f16(bfr[1][2], hf2, acc1, 0, 0, 0);
        acc2 = __builtin_amdgcn_mfma_f32_16x16x32_f16(bfr[2][2], hf2, acc2, 0, 0, 0);
        if (has4) acc3 = __builtin_amdgcn_mfma_f32_16x16x32_f16(bfr[3][2], hf2, acc3, 0, 0, 0);
        acc0 = __builtin_amdgcn_mfma_f32_16x16x32_f16(bfr[0][3], hf3, acc0, 0, 0, 0);
        acc1 = __builtin_amdgcn_mfma_f32_16x16x32_f16(bfr[1][3], hf3, acc1, 0, 0, 0);
        acc2 = __builtin_amdgcn_mfma_f32_16x16x32_f16(bfr[2][3], hf3, acc2, 0, 0, 0);
        if (has4) acc3 = __builtin_amdgcn_mfma_f32_16x16x32_f16(bfr[3][3], hf3, acc3, 0, 0, 0);
        // ---- deferred score reduce for step t-1 (overlaps MFMA latency)
        {
            float pr = p_carry;
            pr += __shfl_xor(pr, 4, 64);
            pr += __shfl_xor(pr, 8, 64);
            pr += __shfl_xor(pr, 16, 64);
            pr += __shfl_xor(pr, 32, 64);
            if (l < 4 && t > 0) spw[l][t - 1][w] = pr;   // l = mb
        }
        // ---- select this lane's tile (dup) — explicit cndmask, no indexing
        f32x4 g = acc0;
        g = (dup == 1) ? acc1 : g;
        g = (dup == 2) ? acc2 : g;
        if (has4) g = (dup == 3) ? acc3 : g;
        // ---- gates -> h (acc regs r=0..3 are i,f,g,o for this lane's u)
        float p = 0.f;
        if (act) {
            half2v x01 = __builtin_bit_cast(half2v, xq.x);
            half2v x23 = __builtin_bit_cast(half2v, xq.y);
            float gi = g[0] + (float)x01.x;
            float gf = g[1] + (float)x01.y;
            float gg = g[2] + (float)x23.x;
            float go = g[3] + (float)x23.y;
            float c = sigf(gf) * c_reg + sigf(gi) * tanhfast(gg);
            c_reg = c;
            float hh = sigf(go) * tanhfast(c);
            _Float16 h16 = (_Float16)hh;
            h_cur[(t + 1) & 1][mb][u] = h16;
            oh_lds[mb][t * Hn + u] = h16;
            if (t < slen) sumh += hh;
            if (t == slen - 1) lasth = hh;
            p = hh * lt_reg;
            int tn2 = (t + 2 < Tn) ? t + 2 : Tn - 1;
            xq = xq1;
            xq1 = *(const uint2*)(tb_u + (size_t)widc[mb][tn2]);
        }
        p_carry = p;
        BAR_LDS();  // h(t+1) + spw visible to all waves; vmcnt stays free
    }
    // final deferred reduce for t = Tn-1
    {
        float pr = p_carry;
        pr += __shfl_xor(pr, 4, 64);
        pr += __shfl_xor(pr, 8, 64);
        pr += __shfl_xor(pr, 16, 64);
        pr += __shfl_xor(pr, 32, 64);
        if (l < 4) spw[l][Tn - 1][w] = pr;
    }
    __syncthreads();
    // ---- top-4: wave w<4 handles batch b0+w; tie-break smaller index
    if (w < 4) {
        int sl = sen_len[b0 + w];
        float4 a0 = *(const float4*)&spw[w][l][0];
        float4 a1 = *(const float4*)&spw[w][l][4];
        float4 c0 = *(const float4*)&spw[w][l + 64][0];
        float4 c1 = *(const float4*)&spw[w][l + 64][4];
        float sa = (a0.x + a0.y + a0.z + a0.w) + (a1.x + a1.y + a1.z + a1.w);
        float sb = (c0.x + c0.y + c0.z + c0.w) + (c1.x + c1.y + c1.z + c1.w);
        float s0 = (l < sl) ? sa : -1e30f;
        float s1 = (l + 64 < sl) ? sb : -1e30f;
        bool tk0 = false, tk1 = false;
#pragma unroll
        for (int p4 = 0; p4 < 4; p4++) {
            float v = tk0 ? -1e30f : s0;
            int ix = l;
            float v1 = tk1 ? -1e30f : s1;
            if (v1 > v) { v = v1; ix = l + 64; }
            for (int off = 32; off; off >>= 1) {
                float ov = __shfl_down(v, off, 64);
                int oi = __shfl_down(ix, off, 64);
                if (ov > v || (ov == v && oi < ix)) { v = ov; ix = oi; }
            }
            v = __shfl(v, 0, 64);
            ix = __shfl(ix, 0, 64);
            if (l == 0) { tk_val[w][p4] = v; tk_idx[w][p4] = ix; }
            if (ix == l) tk0 = true;
            if (ix == l + 64) tk1 = true;
        }
    }
    __syncthreads();
    // ---- pos / neg / lasth (one item per lane; gathers from LDS)
    if (act) {
        float pos = 0.f, nsum = sumh;
#pragma unroll
        for (int p4 = 0; p4 < 4; p4++) {
            int ix = tk_idx[mb][p4];
            float r = (float)oh_lds[mb][ix * Hn + u];
            pos += tk_val[mb][p4] * r;
            nsum -= r;
        }
        pos_sh[mb][u] = pos;
        lasth_sh[mb][u] = lasth;
        neg_sh[mb][u] = nsum;
    }
    __syncthreads();
    // ---- projections: out_f = lin(lasth), l_rep = lin(pos), pn6 = lin0(neg)
    if (tid < 72) {
        int which = tid / 24, r = tid - which * 24;
        int pmb = r / 6, o = r - pmb * 6;
        const float* src = (which == 0) ? &lasth_sh[pmb][0]
                         : (which == 1) ? &pos_sh[pmb][0] : &neg_sh[pmb][0];
        float acc2 = (which == 2) ? 0.f : linb[o];
        for (int uu = 0; uu < Hn; uu++) acc2 += src[uu] * linW[o * Hn + uu];
        if (which == 0)      d_out[(b0 + pmb) * 6 + o] = acc2;
        else if (which == 1) d_out[Bn * 6 + (b0 + pmb) * 6 + o] = acc2;
        else                 pn6[(b0 + pmb) * 6 + o] = acc2;  // bias added post-cumsum
    }
}

// -------- K4: r_rep = cumsum_b(pn6) + linb (wave-shuffle scan, writes d_out) -
__global__ __launch_bounds__(1024) void k_scan6(const float* __restrict__ pn6,
                                                const float* __restrict__ linb,
                                                float* __restrict__ d_out) {
    __shared__ float wsum[16];
    __shared__ float wpre[16];
    int o = blockIdx.x, t = threadIdx.x;
    int lane = t & 63, wv = t >> 6;
    float v = pn6[t * 6 + o];
#pragma unroll
    for (int off = 1; off < 64; off <<= 1) {
        float x = __shfl_up(v, off, 64);
        if (lane >= off) v += x;
    }
    if (lane == 63) wsum[wv] = v;
    __syncthreads();
    if (t < 16) {
        float s = wsum[t];
#pragma unroll
        for (int off = 1; off < 16; off <<= 1) {
            float x = __shfl_up(s, off, 64);
            if (t >= off) s += x;
        }
        wpre[t] = s;
    }
    __syncthreads();
    float pre = wv ? wpre[wv - 1] : 0.f;
    d_out[2 * Bn * 6 + t * 6 + o] = v + pre + linb[o];
}

extern "C" void kernel_launch(void* const* d_in, const int* in_sizes, int n_in,
                              void* d_out, int out_size, void* d_ws, size_t ws_size,
                              hipStream_t stream) {
    const int*   word_id = (const int*)d_in[0];
    const int*   sen_len = (const int*)d_in[1];
    const int*   lwid    = (const int*)d_in[2];
    const float* emb     = (const float*)d_in[3];
    const float* W_ih    = (const float*)d_in[4];
    const float* W_hh    = (const float*)d_in[5];
    const float* b_ih    = (const float*)d_in[6];
    const float* b_hh    = (const float*)d_in[7];
    const float* linW    = (const float*)d_in[8];
    const float* linb    = (const float*)d_in[9];
    const float* llW     = (const float*)d_in[10];
    const float* llb     = (const float*)d_in[11];

    char* ws = (char*)d_ws;
    _Float16* table  = (_Float16*)(ws + OFF_TABLE);
    uint4*    wfrag  = (uint4*)(ws + OFF_WFRAG);
    uint4*    wfragB = (uint4*)(ws + OFF_WFRAGB);
    float*    llwt   = (float*)(ws + OFF_LLWT);
    float*    lvp    = (float*)(ws + OFF_LV);
    float*    pn6    = (float*)(ws + OFF_PN6);
    float*    outp   = (float*)d_out;

    k_prep<<<118, 256, 0, stream>>>(W_ih, W_hh, llW, wfrag, wfragB, llwt);
    k_table<<<(MPn / 64) * 2, 256, 0, stream>>>(emb, wfragB, b_ih, b_hh, table);
    k_label<<<Bn, 256, 0, stream>>>(lwid, emb, llwt, llb, lvp);
    k_lstm<<<Bn / 4, 512, 0, stream>>>(word_id, sen_len, table, wfrag, lvp, linW, linb, pn6, outp);
    k_scan6<<<6, 1024, 0, stream>>>(pn6, linb, outp);
}

// Round 12
// 257.915 us; speedup vs baseline: 1.5806x; 1.0603x over previous
//
#include <hip/hip_runtime.h>
#include <hip/hip_bf16.h>
#include <cstdint>

// Problem constants
#define Bn   1024
#define Tn   128
#define En   300
#define Hn   100
#define Vn   50000
#define G4n  400   // 4*H
#define MPn  50048 // V padded to mult of 64
#define NPn  448   // 4H padded to mult of 16 (28 n-tiles; only 25 are real)
// gate-column PERMUTATION: jp = 4*u + q  <->  j = q*100 + u  (q = gate i,f,g,o)

typedef __bf16 bf16x8 __attribute__((ext_vector_type(8)));
typedef _Float16 half8 __attribute__((ext_vector_type(8)));
typedef _Float16 half2v __attribute__((ext_vector_type(2)));
typedef float  f32x4  __attribute__((ext_vector_type(4)));

// workspace byte offsets
#define OFF_TABLE  0ull         // f16 [Vn][448] permuted cols   44,800,000
#define OFF_WFRAG  44800000ull  // uint4 [28*4*64] W_hh frags       114,688
#define OFF_WFRAGB 44914688ull  // uint4 [10*28*64] W_ih frags      286,720
#define OFF_LLWT   45201408ull  // f32 [300][100] llW transposed    120,000
#define OFF_LV     45321408ull  // f32 [Bn][Hn]                     409,600
#define OFF_PN6    45731008ull  // f32 [Bn][6]                       24,576

// fast sigmoid/tanh: v_rcp_f32 (1 instr) instead of IEEE divide (~9 instr).
__device__ __forceinline__ float sigf(float x) {
    return __builtin_amdgcn_rcpf(1.0f + __expf(-x));
}
__device__ __forceinline__ float tanhfast(float x) {
    return 1.0f - 2.0f * __builtin_amdgcn_rcpf(__expf(2.0f * x) + 1.0f);
}

// LDS-only barrier: drain lgkmcnt but leave vmcnt free-running so the table
// gather prefetch stays in flight across the barrier.
#define BAR_LDS() do {                                         \
    asm volatile("s_waitcnt lgkmcnt(0)" ::: "memory");          \
    __builtin_amdgcn_s_barrier();                               \
    asm volatile("" ::: "memory");                              \
} while (0)

// -------- K0: W_hh -> f16 frags; W_ih -> bf16 frags; llW -> transposed -------
__global__ void k_prep(const float* __restrict__ W_ih, const float* __restrict__ W_hh,
                       const float* __restrict__ llW,
                       uint4* __restrict__ wfrag, uint4* __restrict__ wfragB,
                       float* __restrict__ llwt) {
    int idx = blockIdx.x * 256 + threadIdx.x;
    if (idx < 28 * 4 * 64) {  // lane holds W[n=nt*16+(l&15)][k=kc*32+(l>>4)*8+j]
        int lane = idx & 63, tk = idx >> 6;
        int nt = tk >> 2, kc = tk & 3;
        int n = nt * 16 + (lane & 15);
        int k0 = kc * 32 + (lane >> 4) * 8;
        int q = n & 3, u = n >> 2;
        union { _Float16 h[8]; uint4 v; } pk;
#pragma unroll
        for (int j = 0; j < 8; j++) {
            int k = k0 + j;
            pk.h[j] = (_Float16)((u < Hn && k < Hn) ? W_hh[(size_t)(q * Hn + u) * Hn + k] : 0.0f);
        }
        wfrag[idx] = pk.v;
    }
    if (idx < 10 * 28 * 64) {  // W_ih frag (bf16): kc-major
        int lane = idx & 63, tk = idx >> 6;
        int kc = tk / 28, nsg = tk - kc * 28;
        int n = nsg * 16 + (lane & 15);
        int k0 = kc * 32 + (lane >> 4) * 8;
        int q = n & 3, u = n >> 2;
        union { __bf16 h[8]; uint4 v; } pk;
#pragma unroll
        for (int j = 0; j < 8; j++) {
            int k = k0 + j;
            pk.h[j] = (__bf16)((u < Hn && k < En) ? W_ih[(size_t)(q * Hn + u) * En + k] : 0.0f);
        }
        wfragB[idx] = pk.v;
    }
    if (idx < En * Hn) {  // llwt[k][h] = llW[h][k]
        int k = idx / Hn, h = idx - k * Hn;
        llwt[idx] = llW[(size_t)h * En + k];
    }
}

// -------- K1: table = emb @ W_ih^T + b (permuted cols, f16 out) --------------
// Swapped-operand epilogue (R11): lane holds 4 consecutive n for one m ->
// one 8-byte store per n-tile.
__global__ __launch_bounds__(256, 2) void k_table(
    const float* __restrict__ emb, const uint4* __restrict__ wfragB,
    const float* __restrict__ b_ih, const float* __restrict__ b_hh,
    _Float16* __restrict__ table) {
    __shared__ __bf16 a_sh[64][328];   // 41,984 B (stride 328: rows offset 4 banks)
    const int tid = threadIdx.x;
    const int mt = blockIdx.x >> 1, nh = blockIdx.x & 1;

    // stage A: 64 rows x 320 cols (zeros past 300)
#pragma unroll
    for (int it = 0; it < 5; it++) {
        int x = it * 256 + tid;            // 0..1279
        int row = x / 20, seg = x - row * 20;
        int gr = mt * 64 + row;
        const float* ar = emb + (size_t)(gr < Vn ? gr : Vn - 1) * En;
        int c0 = seg * 16;
        union { __bf16 h[16]; bf16x8 v[2]; } pk;
#pragma unroll
        for (int g = 0; g < 4; g++) {
            int c = c0 + g * 4;
            if (c + 4 <= En) {
                float4 f = *(const float4*)(ar + c);
                pk.h[g * 4 + 0] = (__bf16)f.x; pk.h[g * 4 + 1] = (__bf16)f.y;
                pk.h[g * 4 + 2] = (__bf16)f.z; pk.h[g * 4 + 3] = (__bf16)f.w;
            } else {
                pk.h[g * 4 + 0] = (__bf16)0.f; pk.h[g * 4 + 1] = (__bf16)0.f;
                pk.h[g * 4 + 2] = (__bf16)0.f; pk.h[g * 4 + 3] = (__bf16)0.f;
            }
        }
        *(bf16x8*)&a_sh[row][c0] = pk.v[0];
        *(bf16x8*)&a_sh[row][c0 + 8] = pk.v[1];
    }
    __syncthreads();

    const int wv = tid >> 6, l = tid & 63;
    const int c16 = l & 15, quad = l >> 4;
    f32x4 acc[14];
#pragma unroll
    for (int i = 0; i < 14; i++) acc[i] = (f32x4){0.f, 0.f, 0.f, 0.f};

    uint4 bcur[14];
#pragma unroll
    for (int ns = 0; ns < 14; ns++) bcur[ns] = wfragB[((0 * 28 + nh * 14 + ns) << 6) + l];

    for (int kc = 0; kc < 10; kc++) {
        uint4 bnxt[14];
        if (kc < 9) {
#pragma unroll
            for (int ns = 0; ns < 14; ns++) bnxt[ns] = wfragB[(((kc + 1) * 28 + nh * 14 + ns) << 6) + l];
        }
        bf16x8 af = *(const bf16x8*)&a_sh[wv * 16 + c16][kc * 32 + quad * 8];
#pragma unroll
        for (int ns = 0; ns < 14; ns++)
            acc[ns] = __builtin_amdgcn_mfma_f32_16x16x32_bf16(__builtin_bit_cast(bf16x8, bcur[ns]), af, acc[ns], 0, 0, 0);
        if (kc < 9) {
#pragma unroll
            for (int ns = 0; ns < 14; ns++) bcur[ns] = bnxt[ns];
        }
    }
    // epilogue (swapped): lane (c16,quad) holds n = n0..n0+3 for m.
    const int m = mt * 64 + wv * 16 + c16;
    if (m < Vn) {
        _Float16* trow = table + (size_t)m * NPn;
#pragma unroll
        for (int ns = 0; ns < 14; ns++) {
            int n0 = (nh * 14 + ns) * 16 + quad * 4;
            int u = n0 >> 2;                       // = (nh*14+ns)*4 + quad
            union { _Float16 h[4]; uint2 v; } pk;
            if (u < Hn) {
#pragma unroll
                for (int r = 0; r < 4; r++) {
                    int j = r * Hn + u;            // q = r (n0 is mult of 4)
                    pk.h[r] = (_Float16)(acc[ns][r] + b_ih[j] + b_hh[j]);
                }
            } else {
                pk.h[0] = (_Float16)0.f; pk.h[1] = (_Float16)0.f;
                pk.h[2] = (_Float16)0.f; pk.h[3] = (_Float16)0.f;
            }
            *(uint2*)(trow + n0) = pk.v;
        }
    }
}

// -------- K2: label_vec = emb[lid] @ ll_W^T + ll_b (2-way K split) -----------
__global__ void k_label(const int* __restrict__ lwid, const float* __restrict__ emb,
                        const float* __restrict__ llwt, const float* __restrict__ llb,
                        float* __restrict__ lv) {
    __shared__ float er[En];
    __shared__ float part[Hn];
    int b = blockIdx.x;
    int lid = lwid[b];
    for (int k = threadIdx.x; k < En; k += 256) er[k] = emb[(size_t)lid * En + k];
    __syncthreads();
    int h = threadIdx.x & 127, half = threadIdx.x >> 7;
    float acc = 0.f;
    if (h < Hn) {
        int k0 = half * 150, k1 = k0 + 150;
        for (int k = k0; k < k1; k++) acc += er[k] * llwt[k * Hn + h];
        if (half == 1) part[h] = acc;
    }
    __syncthreads();
    if (h < Hn && half == 0) lv[(size_t)b * Hn + h] = acc + part[h] + llb[h];
}

// -------- K3: fused LSTM, 4 batch/block, 8 waves, SWAPPED-OPERAND MFMA -------
// R12: score compute MOVED OUT of the per-step loop. The 4-deep shfl_xor
// chain (4 serial ds_bpermute, ~240-300cy on the lgkm-drain path every step)
// + spw write + p math are deleted from the loop; instead a post-loop phase
// computes s[mb][t] = dot(oh[mb][t][:], lt_sh[mb][:]) with thread (mb,t)
// (exactly 512 threads), ~50 paired-f16 FMAs each, once. oh rows get stride
// 102 (51 dwords, odd -> conflict-free score-phase reads).
__global__ __launch_bounds__(512, 2) void k_lstm(
    const int* __restrict__ word_id, const int* __restrict__ sen_len,
    const _Float16* __restrict__ table, const uint4* __restrict__ wfrag,
    const float* __restrict__ lv, const float* __restrict__ linW,
    const float* __restrict__ linb, float* __restrict__ pn6,
    float* __restrict__ d_out) {
    __shared__ __align__(16) _Float16 h_cur[2][4][144];   // [parity][mb][144], cols>=100 zero
    __shared__ __align__(16) _Float16 oh_lds[4][13056];   // [mb][t*102+u]
    __shared__ __align__(16) float    lt_sh[4][Hn];       // label vecs
    __shared__ __align__(16) float    spw2[4][Tn];        // scores [mb][t]
    __shared__ int      widc[4][Tn];                      // premultiplied wid*NPn
    __shared__ float    pos_sh[4][Hn];
    __shared__ float    lasth_sh[4][Hn];
    __shared__ float    neg_sh[4][Hn];
    __shared__ float    tk_val[4][4];
    __shared__ int      tk_idx[4][4];

    const int tid = threadIdx.x;
    const int w = tid >> 6, l = tid & 63;
    const int c16 = l & 15, quad = l >> 4;
    const int b0 = blockIdx.x * 4;

    // init: zero both h parities (incl. padding cols); stage word ids + lt
    for (int i = tid; i < 576; i += 512) ((uint32_t*)h_cur)[i] = 0u;
    { int imb = tid >> 7, it = tid & 127; widc[imb][it] = word_id[(b0 + imb) * Tn + it] * NPn; }
    if (tid < 400) {
        int imb = tid / 100, iu = tid - imb * 100;
        lt_sh[imb][iu] = lv[(size_t)(b0 + imb) * Hn + iu];
    }

    // wave tile assignment over the 25 REAL tiles: w0 -> 4 tiles, w1..7 -> 3.
    const bool has4 = (w == 0);
    const int TB = has4 ? 0 : 4 + 3 * (w - 1);
    const int NT = has4 ? 4 : 3;

    // persistent W_hh fragments — the A operand
    half8 bfr[4][4];
#pragma unroll
    for (int kc = 0; kc < 4; kc++) {
        bfr[0][kc] = __builtin_bit_cast(half8, wfrag[((TB + 0) * 4 + kc) * 64 + l]);
        bfr[1][kc] = __builtin_bit_cast(half8, wfrag[((TB + 1) * 4 + kc) * 64 + l]);
        bfr[2][kc] = __builtin_bit_cast(half8, wfrag[((TB + 2) * 4 + kc) * 64 + l]);
        if (has4) bfr[3][kc] = __builtin_bit_cast(half8, wfrag[((TB + 3) * 4 + kc) * 64 + l]);
    }

    // lane work identity: dup group selects the consumed tile
    const int mb = c16 & 3, dup = c16 >> 2;
    const bool act = (dup < NT);
    const int u = (TB + dup) * 4 + quad;     // <100 whenever act
    const int slen = act ? sen_len[b0 + mb] : 0;
    const _Float16* tb_u = table + u * 4;
    _Float16* ohp = &oh_lds[mb][u];          // walks +102 per step (act lanes)

    __syncthreads();

    uint2 xq = {0, 0}, xq1 = {0, 0};
    if (act) {
        xq  = *(const uint2*)(tb_u + (size_t)widc[mb][0]);
        xq1 = *(const uint2*)(tb_u + (size_t)widc[mb][1]);
    }

    float c_reg = 0.f, sumh = 0.f, lasth = 0.f;

    for (int t = 0; t < Tn; t++) {
        // ---- B-fragments: h for batch c16&3
        const _Float16* hp = &h_cur[t & 1][0][0];
        half8 hf0 = *(const half8*)(hp + (c16 & 3) * 144 + 0 * 32 + quad * 8);
        half8 hf1 = *(const half8*)(hp + (c16 & 3) * 144 + 1 * 32 + quad * 8);
        half8 hf2 = *(const half8*)(hp + (c16 & 3) * 144 + 2 * 32 + quad * 8);
        half8 hf3 = *(const half8*)(hp + (c16 & 3) * 144 + 3 * 32 + quad * 8);
        // ---- MFMA: D = W_hh . h  (gates land lane-local)
        f32x4 acc0, acc1, acc2, acc3;
        acc0 = __builtin_amdgcn_mfma_f32_16x16x32_f16(bfr[0][0], hf0, (f32x4){0.f, 0.f, 0.f, 0.f}, 0, 0, 0);
        acc1 = __builtin_amdgcn_mfma_f32_16x16x32_f16(bfr[1][0], hf0, (f32x4){0.f, 0.f, 0.f, 0.f}, 0, 0, 0);
        acc2 = __builtin_amdgcn_mfma_f32_16x16x32_f16(bfr[2][0], hf0, (f32x4){0.f, 0.f, 0.f, 0.f}, 0, 0, 0);
        if (has4) acc3 = __builtin_amdgcn_mfma_f32_16x16x32_f16(bfr[3][0], hf0, (f32x4){0.f, 0.f, 0.f, 0.f}, 0, 0, 0);
        acc0 = __builtin_amdgcn_mfma_f32_16x16x32_f16(bfr[0][1], hf1, acc0, 0, 0, 0);
        acc1 = __builtin_amdgcn_mfma_f32_16x16x32_f16(bfr[1][1], hf1, acc1, 0, 0, 0);
        acc2 = __builtin_amdgcn_mfma_f32_16x16x32_f16(bfr[2][1], hf1, acc2, 0, 0, 0);
        if (has4) acc3 = __builtin_amdgcn_mfma_f32_16x16x32_f16(bfr[3][1], hf1, acc3, 0, 0, 0);
        acc0 = __builtin_amdgcn_mfma_f32_16x16x32_f16(bfr[0][2], hf2, acc0, 0, 0, 0);
        acc1 = __builtin_amdgcn_mfma_f32_16x16x32_f16(bfr[1][2], hf2, acc1, 0, 0, 0);
        acc2 = __builtin_amdgcn_mfma_f32_16x16x32_f16(bfr[2][2], hf2, acc2, 0, 0, 0);
        if (has4) acc3 = __builtin_amdgcn_mfma_f32_16x16x32_f16(bfr[3][2], hf2, acc3, 0, 0, 0);
        acc0 = __builtin_amdgcn_mfma_f32_16x16x32_f16(bfr[0][3], hf3, acc0, 0, 0, 0);
        acc1 = __builtin_amdgcn_mfma_f32_16x16x32_f16(bfr[1][3], hf3, acc1, 0, 0, 0);
        acc2 = __builtin_amdgcn_mfma_f32_16x16x32_f16(bfr[2][3], hf3, acc2, 0, 0, 0);
        if (has4) acc3 = __builtin_amdgcn_mfma_f32_16x16x32_f16(bfr[3][3], hf3, acc3, 0, 0, 0);
        // ---- select this lane's tile (dup) — explicit cndmask, no indexing
        f32x4 g = acc0;
        g = (dup == 1) ? acc1 : g;
        g = (dup == 2) ? acc2 : g;
        if (has4) g = (dup == 3) ? acc3 : g;
        // ---- gates -> h (acc regs r=0..3 are i,f,g,o for this lane's u)
        if (act) {
            half2v x01 = __builtin_bit_cast(half2v, xq.x);
            half2v x23 = __builtin_bit_cast(half2v, xq.y);
            float gi = g[0] + (float)x01.x;
            float gf = g[1] + (float)x01.y;
            float gg = g[2] + (float)x23.x;
            float go = g[3] + (float)x23.y;
            float c = sigf(gf) * c_reg + sigf(gi) * tanhfast(gg);
            c_reg = c;
            float hh = sigf(go) * tanhfast(c);
            _Float16 h16 = (_Float16)hh;
            h_cur[(t + 1) & 1][mb][u] = h16;
            ohp[0] = h16;
            ohp += 102;
            if (t < slen) sumh += hh;
            if (t == slen - 1) lasth = hh;
            int tn2 = (t + 2 < Tn) ? t + 2 : Tn - 1;
            xq = xq1;
            xq1 = *(const uint2*)(tb_u + (size_t)widc[mb][tn2]);
        }
        BAR_LDS();  // h(t+1) visible to all waves; vmcnt stays free
    }
    // ---- post-loop score phase: thread (mb,t) dots oh row vs lt_sh
    {
        int smb = tid >> 7, st = tid & 127;
        const _Float16* orow = &oh_lds[smb][st * 102];
        const float* lrow = &lt_sh[smb][0];
        float s = 0.f;
#pragma unroll 5
        for (int uu = 0; uu < 100; uu += 2) {
            half2v hv = *(const half2v*)(orow + uu);
            s += (float)hv.x * lrow[uu] + (float)hv.y * lrow[uu + 1];
        }
        spw2[smb][st] = s;
    }
    __syncthreads();
    // ---- top-4: wave w<4 handles batch b0+w; tie-break smaller index
    if (w < 4) {
        int sl = sen_len[b0 + w];
        float s0 = (l < sl) ? spw2[w][l] : -1e30f;
        float s1 = (l + 64 < sl) ? spw2[w][l + 64] : -1e30f;
        bool tk0 = false, tk1 = false;
#pragma unroll
        for (int p4 = 0; p4 < 4; p4++) {
            float v = tk0 ? -1e30f : s0;
            int ix = l;
            float v1 = tk1 ? -1e30f : s1;
            if (v1 > v) { v = v1; ix = l + 64; }
            for (int off = 32; off; off >>= 1) {
                float ov = __shfl_down(v, off, 64);
                int oi = __shfl_down(ix, off, 64);
                if (ov > v || (ov == v && oi < ix)) { v = ov; ix = oi; }
            }
            v = __shfl(v, 0, 64);
            ix = __shfl(ix, 0, 64);
            if (l == 0) { tk_val[w][p4] = v; tk_idx[w][p4] = ix; }
            if (ix == l) tk0 = true;
            if (ix == l + 64) tk1 = true;
        }
    }
    __syncthreads();
    // ---- pos / neg / lasth (one item per lane; gathers from LDS)
    if (act) {
        float pos = 0.f, nsum = sumh;
#pragma unroll
        for (int p4 = 0; p4 < 4; p4++) {
            int ix = tk_idx[mb][p4];
            float r = (float)oh_lds[mb][ix * 102 + u];
            pos += tk_val[mb][p4] * r;
            nsum -= r;
        }
        pos_sh[mb][u] = pos;
        lasth_sh[mb][u] = lasth;
        neg_sh[mb][u] = nsum;
    }
    __syncthreads();
    // ---- projections: out_f = lin(lasth), l_rep = lin(pos), pn6 = lin0(neg)
    if (tid < 72) {
        int which = tid / 24, r = tid - which * 24;
        int pmb = r / 6, o = r - pmb * 6;
        const float* src = (which == 0) ? &lasth_sh[pmb][0]
                         : (which == 1) ? &pos_sh[pmb][0] : &neg_sh[pmb][0];
        float acc2 = (which == 2) ? 0.f : linb[o];
        for (int uu = 0; uu < Hn; uu++) acc2 += src[uu] * linW[o * Hn + uu];
        if (which == 0)      d_out[(b0 + pmb) * 6 + o] = acc2;
        else if (which == 1) d_out[Bn * 6 + (b0 + pmb) * 6 + o] = acc2;
        else                 pn6[(b0 + pmb) * 6 + o] = acc2;  // bias added post-cumsum
    }
}

// -------- K4: r_rep = cumsum_b(pn6) + linb (wave-shuffle scan, writes d_out) -
__global__ __launch_bounds__(1024) void k_scan6(const float* __restrict__ pn6,
                                                const float* __restrict__ linb,
                                                float* __restrict__ d_out) {
    __shared__ float wsum[16];
    __shared__ float wpre[16];
    int o = blockIdx.x, t = threadIdx.x;
    int lane = t & 63, wv = t >> 6;
    float v = pn6[t * 6 + o];
#pragma unroll
    for (int off = 1; off < 64; off <<= 1) {
        float x = __shfl_up(v, off, 64);
        if (lane >= off) v += x;
    }
    if (lane == 63) wsum[wv] = v;
    __syncthreads();
    if (t < 16) {
        float s = wsum[t];
#pragma unroll
        for (int off = 1; off < 16; off <<= 1) {
            float x = __shfl_up(s, off, 64);
            if (t >= off) s += x;
        }
        wpre[t] = s;
    }
    __syncthreads();
    float pre = wv ? wpre[wv - 1] : 0.f;
    d_out[2 * Bn * 6 + t * 6 + o] = v + pre + linb[o];
}

extern "C" void kernel_launch(void* const* d_in, const int* in_sizes, int n_in,
                              void* d_out, int out_size, void* d_ws, size_t ws_size,
                              hipStream_t stream) {
    const int*   word_id = (const int*)d_in[0];
    const int*   sen_len = (const int*)d_in[1];
    const int*   lwid    = (const int*)d_in[2];
    const float* emb     = (const float*)d_in[3];
    const float* W_ih    = (const float*)d_in[4];
    const float* W_hh    = (const float*)d_in[5];
    const float* b_ih    = (const float*)d_in[6];
    const float* b_hh    = (const float*)d_in[7];
    const float* linW    = (const float*)d_in[8];
    const float* linb    = (const float*)d_in[9];
    const float* llW     = (const float*)d_in[10];
    const float* llb     = (const float*)d_in[11];

    char* ws = (char*)d_ws;
    _Float16* table  = (_Float16*)(ws + OFF_TABLE);
    uint4*    wfrag  = (uint4*)(ws + OFF_WFRAG);
    uint4*    wfragB = (uint4*)(ws + OFF_WFRAGB);
    float*    llwt   = (float*)(ws + OFF_LLWT);
    float*    lvp    = (float*)(ws + OFF_LV);
    float*    pn6    = (float*)(ws + OFF_PN6);
    float*    outp   = (float*)d_out;

    k_prep<<<118, 256, 0, stream>>>(W_ih, W_hh, llW, wfrag, wfragB, llwt);
    k_table<<<(MPn / 64) * 2, 256, 0, stream>>>(emb, wfragB, b_ih, b_hh, table);
    k_label<<<Bn, 256, 0, stream>>>(lwid, emb, llwt, llb, lvp);
    k_lstm<<<Bn / 4, 512, 0, stream>>>(word_id, sen_len, table, wfrag, lvp, linW, linb, pn6, outp);
    k_scan6<<<6, 1024, 0, stream>>>(pn6, linb, outp);
}